// Round 15
// baseline (125.528 us; speedup 1.0000x reference)
//
#include <hip/hip_runtime.h>
#include <hip/hip_bf16.h>

typedef __attribute__((ext_vector_type(8))) __bf16 bf16x8;
typedef __attribute__((ext_vector_type(4))) short short4v;
typedef __attribute__((ext_vector_type(4))) float f32x4;

#define MFMA(a,b,c) __builtin_amdgcn_mfma_f32_16x16x32_bf16((a),(b),(c),0,0,0)
// K=16 bf16 MFMA: A[row=c][k=g*4+j], B[k=g*4+j][col=c], D[row=g*4+j][col=c].
#define MFMA16(a,b,c) __builtin_amdgcn_mfma_f32_16x16x16bf16_1k((a),(b),(c),0,0,0)

// LDS layout (64 KB, 2 blocks/CU):
//  XB 0..16K   : x  [64][128] bf16 (swz256)
//  QB 16K..32K : q  [64][128] bf16 (swz256); wave w owns cols 32w..32w+31;
//                ob overwrites the SAME cols after S (own-wave, no race)
//  KB 32K..48K : k  [64][128] bf16 (swz256); wave w owns cols 32w..+31
//  VT 48K..64K : v^T [128][64] bf16 (swz128); wave w owns rows 32w..+31
#define XB 0u
#define QB 16384u
#define KB 32768u
#define VT 49152u

static __device__ __forceinline__ unsigned short f2u(float x) {
  return __builtin_bit_cast(unsigned short, static_cast<__bf16>(x));
}
// cvt_pk-friendly packs (compiler emits v_cvt_pk_bf16_f32).
static __device__ __forceinline__ unsigned long long pack4(float a, float b, float c, float d) {
  union { __bf16 h[4]; unsigned long long u; } z;
  z.h[0] = static_cast<__bf16>(a);
  z.h[1] = static_cast<__bf16>(b);
  z.h[2] = static_cast<__bf16>(c);
  z.h[3] = static_cast<__bf16>(d);
  return z.u;
}
static __device__ __forceinline__ unsigned long long pack4v(f32x4 v) {
  return pack4(v[0], v[1], v[2], v[3]);
}
static __device__ __forceinline__ short4v pack4s(float a, float b, float c, float d) {
  union { __bf16 h[4]; short4v s; } z;
  z.h[0] = static_cast<__bf16>(a);
  z.h[1] = static_cast<__bf16>(b);
  z.h[2] = static_cast<__bf16>(c);
  z.h[3] = static_cast<__bf16>(d);
  return z.s;
}
static __device__ __forceinline__ unsigned sw256(unsigned row, unsigned colb) {
  return (row << 8) + (colb ^ ((row & 7u) << 4));
}
static __device__ __forceinline__ unsigned sw128(unsigned row, unsigned colb) {
  return (row << 7) + (colb ^ ((row & 7u) << 4));
}

// ---------------- prep: weights -> bf16 (Wq pre-scaled by SCALE*log2e), bias gather ----------------
__global__ void rsa_prep(const float* __restrict__ qk_w, const float* __restrict__ v_w,
                         const float* __restrict__ proj_w, const float* __restrict__ bias_table,
                         unsigned short* __restrict__ wqk, unsigned short* __restrict__ wv,
                         unsigned short* __restrict__ wp, float* __restrict__ biasNN) {
  const float QSCALE = 0.17677669529663687f * 1.4426950408889634f;  // 32^-0.5 * log2(e)
  const float LOG2E = 1.4426950408889634f;
  int t = blockIdx.x * blockDim.x + threadIdx.x;
  int stride = gridDim.x * blockDim.x;
  for (int i = t; i < 256 * 128; i += stride) {
    float v = qk_w[i];
    if (i < 128 * 128) v *= QSCALE;          // q-half pre-scaled (softmax uses exp2)
    wqk[i] = f2u(v);
  }
  for (int i = t; i < 128 * 128; i += stride) wv[i] = f2u(v_w[i]);
  for (int i = t; i < 128 * 128; i += stride) wp[i] = f2u(proj_w[i]);
  for (int i = t; i < 4 * 64 * 64; i += stride) {
    int h = i >> 12, r = (i >> 6) & 63, m = i & 63;
    float v = -1e9f;                          // pad: exp2(-1.44e9) = 0
    if (r < 49 && m < 49) {
      int ri = r / 7, rj = r - ri * 7, mi = m / 7, mj = m - mi * 7;
      int rel = (ri - mi + 6) * 13 + (rj - mj + 6);
      v = bias_table[rel * 4 + h];
    }
    biasNN[i] = v * LOG2E;                    // folded for exp2
  }
}

// ---------------- main: 4-wave blocks, wave = head, 2 barriers ----------------
// Wave w computes head-w's q,k,v^T (its own LDS columns), then S/softmax/PV
// read only own writes -> NO barrier between x staging and ob write. The only
// cross-wave dependencies are x (B1) and ob->proj (B4).
__global__ __launch_bounds__(256, 2) void rsa_main(
    const float* __restrict__ x, const float* __restrict__ qk_bias,
    const float* __restrict__ v_bias, const float* __restrict__ proj_bias,
    const unsigned short* __restrict__ wqk, const unsigned short* __restrict__ wv,
    const unsigned short* __restrict__ wp, const float* __restrict__ biasNN,
    float* __restrict__ out) {
  __shared__ __align__(16) unsigned char LDS[65536];
  const int tid = threadIdx.x;
  const int w = tid >> 6;        // wave = head, 0..3
  const int lane = tid & 63;
  const int c = lane & 15;
  const int g = lane >> 4;
  const int b = blockIdx.x;
  const float QBSCALE = 0.17677669529663687f * 1.4426950408889634f;

  // Phase 0: stage x (49x128 f32) -> bf16 LDS [64][128] swizzled, zero-pad rows 49..63
  {
    const f32x4* xp = reinterpret_cast<const f32x4*>(x + (size_t)b * 6272);
    for (int i = tid; i < 1568; i += 256) {
      f32x4 v = xp[i];
      unsigned row = (unsigned)i >> 5, c4 = (unsigned)i & 31u;
      *reinterpret_cast<unsigned long long*>(LDS + XB + sw256(row, c4 * 8)) = pack4v(v);
    }
    for (int i = tid; i < 480; i += 256) {
      unsigned row = 49 + ((unsigned)i >> 5), c4 = (unsigned)i & 31u;
      *reinterpret_cast<unsigned long long*>(LDS + XB + sw256(row, c4 * 8)) = 0ull;
    }
  }
  __syncthreads();  // B1: x visible (only pre-proj barrier)

  // Phase 1a: head-w q tiles {2w,2w+1} and k tiles {2w+8,2w+9} (own LDS cols).
  __builtin_amdgcn_s_setprio(1);
#pragma unroll
  for (int mi = 0; mi < 4; ++mi) {
    const int mt = (mi < 2) ? (2 * w + mi) : (6 + 2 * w + mi);  // q,q,k,k tiles
    bf16x8 a[4];
    const unsigned short* wrow = wqk + (mt * 16 + c) * 128 + g * 8;
#pragma unroll
    for (int ks = 0; ks < 4; ++ks) a[ks] = *reinterpret_cast<const bf16x8*>(wrow + ks * 32);
    f32x4 bias4 = *reinterpret_cast<const f32x4*>(qk_bias + mt * 16 + g * 4);
    if (mi < 2) { bias4[0] *= QBSCALE; bias4[1] *= QBSCALE; bias4[2] *= QBSCALE; bias4[3] *= QBSCALE; }
    f32x4 acc[4];
#pragma unroll
    for (int nt = 0; nt < 4; ++nt) acc[nt] = bias4;
#pragma unroll
    for (int ks = 0; ks < 4; ++ks) {
#pragma unroll
      for (int nt = 0; nt < 4; ++nt) {
        bf16x8 bf = *reinterpret_cast<const bf16x8*>(LDS + XB + sw256(nt * 16 + c, (ks * 32 + g * 8) * 2));
        acc[nt] = MFMA(a[ks], bf, acc[nt]);
      }
    }
    const unsigned base = (mi < 2) ? QB : KB;
    const unsigned colb = ((mt & 7) * 16 + g * 4) * 2;   // q: 32w.. ; k: 32w.. (own cols)
#pragma unroll
    for (int nt = 0; nt < 4; ++nt)
      *reinterpret_cast<unsigned long long*>(LDS + base + sw256(nt * 16 + c, colb)) = pack4v(acc[nt]);
  }

  // Phase 1b: head-w v channels 32w..32w+31 -> v^T rows (own rows).
#pragma unroll
  for (int ci = 0; ci < 2; ++ci) {
    const int ch = w * 32 + ci * 16 + c;
    const float vb = v_bias[ch];
    bf16x8 bw[4];
    const unsigned short* wrow = wv + ch * 128 + g * 8;
#pragma unroll
    for (int ks = 0; ks < 4; ++ks) bw[ks] = *reinterpret_cast<const bf16x8*>(wrow + ks * 32);
    f32x4 acc[4];
#pragma unroll
    for (int mt = 0; mt < 4; ++mt) acc[mt] = f32x4{vb, vb, vb, vb};
#pragma unroll
    for (int ks = 0; ks < 4; ++ks) {
#pragma unroll
      for (int mt = 0; mt < 4; ++mt) {
        bf16x8 af = *reinterpret_cast<const bf16x8*>(LDS + XB + sw256(mt * 16 + c, (ks * 32 + g * 8) * 2));
        acc[mt] = MFMA(af, bw[ks], acc[mt]);
      }
    }
#pragma unroll
    for (int mt = 0; mt < 4; ++mt)
      *reinterpret_cast<unsigned long long*>(LDS + VT + sw128(ch, (mt * 16 + g * 4) * 2)) =
          pack4v(acc[mt]);
  }
  __builtin_amdgcn_s_setprio(0);
  // NO BARRIER: everything below reads only this wave's own LDS writes
  // (same-wave ds ordering via lgkmcnt).

  // Phase 2a+2b: per token-tile rt: S = K@Q^T (rel-pos bias as acc-init) then
  // softmax (exp2, tree-sum, v_rcp) -> in-register K=16 B-frags pk[rt][mt].
  short4v pk[4][4];
#pragma unroll
  for (int rt = 0; rt < 4; ++rt) {
    f32x4 bbr[4];
    {
      const float* bp = biasNN + ((w * 64 + rt * 16 + c) << 6);
#pragma unroll
      for (int mt = 0; mt < 4; ++mt)
        bbr[mt] = *reinterpret_cast<const f32x4*>(bp + mt * 16 + g * 4);
    }
    bf16x8 qf = *reinterpret_cast<const bf16x8*>(LDS + QB + sw256(rt * 16 + c, w * 64 + g * 16));
    f32x4 s[4];
    __builtin_amdgcn_s_setprio(1);
#pragma unroll
    for (int mt = 0; mt < 4; ++mt) {
      bf16x8 kf = *reinterpret_cast<const bf16x8*>(LDS + KB + sw256(mt * 16 + c, w * 64 + g * 16));
      s[mt] = MFMA(kf, qf, bbr[mt]);
    }
    __builtin_amdgcn_s_setprio(0);
    float v[16];
#pragma unroll
    for (int mt = 0; mt < 4; ++mt) {
#pragma unroll
      for (int j = 0; j < 4; ++j) v[mt * 4 + j] = exp2f(s[mt][j]);
    }
    float p0 = (v[0] + v[1]) + (v[2] + v[3]);
    float p1 = (v[4] + v[5]) + (v[6] + v[7]);
    float p2 = (v[8] + v[9]) + (v[10] + v[11]);
    float p3 = (v[12] + v[13]) + (v[14] + v[15]);
    float sum = (p0 + p1) + (p2 + p3);
    sum += __shfl_xor(sum, 16);
    sum += __shfl_xor(sum, 32);
    const float inv = __builtin_amdgcn_rcpf(sum);
#pragma unroll
    for (int mt = 0; mt < 4; ++mt)
      pk[rt][mt] = pack4s(v[mt * 4] * inv, v[mt * 4 + 1] * inv,
                          v[mt * 4 + 2] * inv, v[mt * 4 + 3] * inv);
  }

  // Phase 2c: O^T = V^T @ P^T via 32 x mfma16 (A-frags = own vt rows).
  f32x4 od[2][4];
  {
    short4v vfrag[2][4];
#pragma unroll
    for (int ct2 = 0; ct2 < 2; ++ct2)
#pragma unroll
      for (int ks = 0; ks < 4; ++ks)
        vfrag[ct2][ks] = *reinterpret_cast<const short4v*>(
            LDS + VT + sw128((w * 2 + ct2) * 16 + c, (ks * 16 + g * 4) * 2));
#pragma unroll
    for (int ct2 = 0; ct2 < 2; ++ct2)
#pragma unroll
      for (int rt = 0; rt < 4; ++rt) od[ct2][rt] = f32x4{0.f, 0.f, 0.f, 0.f};
    __builtin_amdgcn_s_setprio(1);
#pragma unroll
    for (int ks = 0; ks < 4; ++ks)
#pragma unroll
      for (int ct2 = 0; ct2 < 2; ++ct2)
#pragma unroll
        for (int rt = 0; rt < 4; ++rt)
          od[ct2][rt] = MFMA16(vfrag[ct2][ks], pk[rt][ks], od[ct2][rt]);
    __builtin_amdgcn_s_setprio(0);
  }

  // ob writes over OWN q cols in QB (q dead for this wave; no other wave reads them).
#pragma unroll
  for (int ct2 = 0; ct2 < 2; ++ct2)
#pragma unroll
    for (int rt = 0; rt < 4; ++rt) {
      const int r = rt * 16 + c;
      *reinterpret_cast<unsigned long long*>(
          LDS + QB + sw256(r, ((w * 2 + ct2) * 16 + g * 4) * 2)) = pack4v(od[ct2][rt]);
    }
  __syncthreads();  // B4: ob visible (the only cross-head dependency)

  // Phase 3: out^T = Wp @ O^T; wave w: ch tiles {2w, 2w+1}; proj-bias as acc-init.
  __builtin_amdgcn_s_setprio(1);
#pragma unroll
  for (int u = 0; u < 2; ++u) {
    const int ct = 2 * w + u;
    bf16x8 ap[4];
    const unsigned short* wrow = wp + (ct * 16 + c) * 128 + g * 8;
#pragma unroll
    for (int ks = 0; ks < 4; ++ks) ap[ks] = *reinterpret_cast<const bf16x8*>(wrow + ks * 32);
    f32x4 pb4 = *reinterpret_cast<const f32x4*>(proj_bias + ct * 16 + g * 4);
    f32x4 acc[4];
#pragma unroll
    for (int nt = 0; nt < 4; ++nt) acc[nt] = pb4;
#pragma unroll
    for (int ks = 0; ks < 4; ++ks) {
#pragma unroll
      for (int nt = 0; nt < 4; ++nt) {
        bf16x8 bf = *reinterpret_cast<const bf16x8*>(LDS + QB + sw256(nt * 16 + c, (ks * 32 + g * 8) * 2));
        acc[nt] = MFMA(ap[ks], bf, acc[nt]);
      }
    }
#pragma unroll
    for (int nt = 0; nt < 4; ++nt) {
      const int tok = nt * 16 + c;
      if (tok < 49) {
        *reinterpret_cast<f32x4*>(out + ((size_t)b * 49 + tok) * 128 + ct * 16 + g * 4) = acc[nt];
      }
    }
  }
  __builtin_amdgcn_s_setprio(0);
}

extern "C" void kernel_launch(void* const* d_in, const int* in_sizes, int n_in,
                              void* d_out, int out_size, void* d_ws, size_t ws_size,
                              hipStream_t stream) {
  const float* x          = (const float*)d_in[0];
  const float* qk_w       = (const float*)d_in[1];
  const float* qk_b       = (const float*)d_in[2];
  const float* v_w        = (const float*)d_in[3];
  const float* v_b        = (const float*)d_in[4];
  const float* proj_w     = (const float*)d_in[5];
  const float* proj_b     = (const float*)d_in[6];
  const float* bias_table = (const float*)d_in[7];
  float* out = (float*)d_out;

  // workspace carve: wqk bf16 [256*128] | wv [128*128] | wp [128*128] | biasNN f32 [4*64*64]
  unsigned short* wqk = (unsigned short*)d_ws;
  unsigned short* wv  = wqk + 256 * 128;
  unsigned short* wp  = wv + 128 * 128;
  float* biasNN = (float*)((char*)d_ws + 131072);

  const int B = in_sizes[0] / (49 * 128);

  rsa_prep<<<dim3(128), dim3(512), 0, stream>>>(qk_w, v_w, proj_w, bias_table, wqk, wv, wp, biasNN);
  rsa_main<<<dim3(B), dim3(256), 0, stream>>>(x, qk_b, v_b, proj_b, wqk, wv, wp, biasNN, out);
}

// Round 16
// 122.269 us; speedup vs baseline: 1.0267x; 1.0267x over previous
//
#include <hip/hip_runtime.h>
#include <hip/hip_bf16.h>

typedef __attribute__((ext_vector_type(8))) __bf16 bf16x8;
typedef __attribute__((ext_vector_type(4))) short short4v;
typedef __attribute__((ext_vector_type(4))) float f32x4;

#define MFMA(a,b,c) __builtin_amdgcn_mfma_f32_16x16x32_bf16((a),(b),(c),0,0,0)
// K=16 bf16 MFMA: A[row=c][k=g*4+j], B[k=g*4+j][col=c], D[row=g*4+j][col=c].
#define MFMA16(a,b,c) __builtin_amdgcn_mfma_f32_16x16x16bf16_1k((a),(b),(c),0,0,0)

// LDS layout (48 KB -> 3 blocks/CU, 12 waves/CU):
//  XB 0..16K   : x  [64][128] bf16 (swz256)
//  VT 16K..32K : v^T [128][64] bf16 (swz128); wave w owns rows 32w..32w+31
//  OB 32K..48K : ob [64][128] bf16 (swz256); wave w writes cols 32w..+31
#define XB 0u
#define VT 16384u
#define OB 32768u

static __device__ __forceinline__ unsigned short f2u(float x) {
  return __builtin_bit_cast(unsigned short, static_cast<__bf16>(x));
}
// cvt_pk-friendly packs (compiler emits v_cvt_pk_bf16_f32).
static __device__ __forceinline__ unsigned long long pack4(float a, float b, float c, float d) {
  union { __bf16 h[4]; unsigned long long u; } z;
  z.h[0] = static_cast<__bf16>(a);
  z.h[1] = static_cast<__bf16>(b);
  z.h[2] = static_cast<__bf16>(c);
  z.h[3] = static_cast<__bf16>(d);
  return z.u;
}
static __device__ __forceinline__ unsigned long long pack4v(f32x4 v) {
  return pack4(v[0], v[1], v[2], v[3]);
}
static __device__ __forceinline__ short4v pack4s(float a, float b, float c, float d) {
  union { __bf16 h[4]; short4v s; } z;
  z.h[0] = static_cast<__bf16>(a);
  z.h[1] = static_cast<__bf16>(b);
  z.h[2] = static_cast<__bf16>(c);
  z.h[3] = static_cast<__bf16>(d);
  return z.s;
}
static __device__ __forceinline__ short4v pack4sv(f32x4 v) {
  return pack4s(v[0], v[1], v[2], v[3]);
}
static __device__ __forceinline__ unsigned sw256(unsigned row, unsigned colb) {
  return (row << 8) + (colb ^ ((row & 7u) << 4));
}
static __device__ __forceinline__ unsigned sw128(unsigned row, unsigned colb) {
  return (row << 7) + (colb ^ ((row & 7u) << 4));
}

// ---------------- prep: weights -> bf16 (Wq pre-scaled by SCALE*log2e), bias gather ----------------
__global__ void rsa_prep(const float* __restrict__ qk_w, const float* __restrict__ v_w,
                         const float* __restrict__ proj_w, const float* __restrict__ bias_table,
                         unsigned short* __restrict__ wqk, unsigned short* __restrict__ wv,
                         unsigned short* __restrict__ wp, float* __restrict__ biasNN) {
  const float QSCALE = 0.17677669529663687f * 1.4426950408889634f;  // 32^-0.5 * log2(e)
  const float LOG2E = 1.4426950408889634f;
  int t = blockIdx.x * blockDim.x + threadIdx.x;
  int stride = gridDim.x * blockDim.x;
  for (int i = t; i < 256 * 128; i += stride) {
    float v = qk_w[i];
    if (i < 128 * 128) v *= QSCALE;          // q-half pre-scaled (softmax uses exp2)
    wqk[i] = f2u(v);
  }
  for (int i = t; i < 128 * 128; i += stride) wv[i] = f2u(v_w[i]);
  for (int i = t; i < 128 * 128; i += stride) wp[i] = f2u(proj_w[i]);
  for (int i = t; i < 4 * 64 * 64; i += stride) {
    int h = i >> 12, r = (i >> 6) & 63, m = i & 63;
    float v = -1e9f;                          // pad: exp2(-1.44e9) = 0
    if (r < 49 && m < 49) {
      int ri = r / 7, rj = r - ri * 7, mi = m / 7, mj = m - mi * 7;
      int rel = (ri - mi + 6) * 13 + (rj - mj + 6);
      v = bias_table[rel * 4 + h];
    }
    biasNN[i] = v * LOG2E;                    // folded for exp2
  }
}

// ---------------- main: 4-wave blocks, wave = head, ALL-REGISTER q/k/S/P ----------------
// Key identity: phase-1a's output-transposed D layout (lane (c,g) <-> token c,
// channel g*4+j) IS both the A-frag (k) and B-frag (q) layout of the 16x16x16
// MFMA. So q,k stay in registers through S; P stays in registers through PV.
// LDS is used only for x (staged once), v^T (wave-local rows), and ob (proj).
// Barriers: B1 (x), B4 (ob->proj) — 2 total.
__global__ __launch_bounds__(256, 3) void rsa_main(
    const float* __restrict__ x, const float* __restrict__ qk_bias,
    const float* __restrict__ v_bias, const float* __restrict__ proj_bias,
    const unsigned short* __restrict__ wqk, const unsigned short* __restrict__ wv,
    const unsigned short* __restrict__ wp, const float* __restrict__ biasNN,
    float* __restrict__ out) {
  __shared__ __align__(16) unsigned char LDS[49152];
  const int tid = threadIdx.x;
  const int w = tid >> 6;        // wave = head, 0..3
  const int lane = tid & 63;
  const int c = lane & 15;
  const int g = lane >> 4;
  const int b = blockIdx.x;
  const float QBSCALE = 0.17677669529663687f * 1.4426950408889634f;

  // Phase 0: stage x (49x128 f32) -> bf16 LDS [64][128] swizzled, zero-pad rows 49..63
  {
    const f32x4* xp = reinterpret_cast<const f32x4*>(x + (size_t)b * 6272);
    for (int i = tid; i < 1568; i += 256) {
      f32x4 v = xp[i];
      unsigned row = (unsigned)i >> 5, c4 = (unsigned)i & 31u;
      *reinterpret_cast<unsigned long long*>(LDS + XB + sw256(row, c4 * 8)) = pack4v(v);
    }
    for (int i = tid; i < 480; i += 256) {
      unsigned row = 49 + ((unsigned)i >> 5), c4 = (unsigned)i & 31u;
      *reinterpret_cast<unsigned long long*>(LDS + XB + sw256(row, c4 * 8)) = 0ull;
    }
  }
  __syncthreads();  // B1: x visible

  // Loop A: head-w q (ch-tiles 2w,2w+1) + k (same ch range) fused over shared
  // xf reads; output-transposed; biases as acc-init. All-register output.
  f32x4 qacc[2][4], kacc[2][4];
  {
#pragma unroll
    for (int kt = 0; kt < 2; ++kt) {
      f32x4 qb4 = *reinterpret_cast<const f32x4*>(qk_bias + (2 * w + kt) * 16 + g * 4);
      qb4[0] *= QBSCALE; qb4[1] *= QBSCALE; qb4[2] *= QBSCALE; qb4[3] *= QBSCALE;
      f32x4 kb4 = *reinterpret_cast<const f32x4*>(qk_bias + 128 + (2 * w + kt) * 16 + g * 4);
#pragma unroll
      for (int nt = 0; nt < 4; ++nt) { qacc[kt][nt] = qb4; kacc[kt][nt] = kb4; }
    }
    __builtin_amdgcn_s_setprio(1);
#pragma unroll
    for (int ks = 0; ks < 4; ++ks) {
      bf16x8 wq0 = *reinterpret_cast<const bf16x8*>(wqk + ((2 * w) * 16 + c) * 128 + ks * 32 + g * 8);
      bf16x8 wq1 = *reinterpret_cast<const bf16x8*>(wqk + ((2 * w + 1) * 16 + c) * 128 + ks * 32 + g * 8);
      bf16x8 wk0 = *reinterpret_cast<const bf16x8*>(wqk + (128 + (2 * w) * 16 + c) * 128 + ks * 32 + g * 8);
      bf16x8 wk1 = *reinterpret_cast<const bf16x8*>(wqk + (128 + (2 * w + 1) * 16 + c) * 128 + ks * 32 + g * 8);
#pragma unroll
      for (int nt = 0; nt < 4; ++nt) {
        bf16x8 xf = *reinterpret_cast<const bf16x8*>(LDS + XB + sw256(nt * 16 + c, (ks * 32 + g * 8) * 2));
        qacc[0][nt] = MFMA(wq0, xf, qacc[0][nt]);
        qacc[1][nt] = MFMA(wq1, xf, qacc[1][nt]);
        kacc[0][nt] = MFMA(wk0, xf, kacc[0][nt]);
        kacc[1][nt] = MFMA(wk1, xf, kacc[1][nt]);
      }
    }
    __builtin_amdgcn_s_setprio(0);
  }
  // Pack q/k to bf16 MFMA16 fragments; f32 accs die (frees 64 regs).
  // q16[kt][rt] = B-frag (q[tok=rt*16+c][hch=kt*16+g*4+j]);
  // k16[kt][mt] = A-frag (k[tok=mt*16+c][hch=kt*16+g*4+j]).
  short4v q16[2][4], k16[2][4];
#pragma unroll
  for (int kt = 0; kt < 2; ++kt)
#pragma unroll
    for (int nt = 0; nt < 4; ++nt) {
      q16[kt][nt] = pack4sv(qacc[kt][nt]);
      k16[kt][nt] = pack4sv(kacc[kt][nt]);
    }

  // Loop B: head-w v channels (2w,2w+1 tiles) -> VT rows (wave-local).
  __builtin_amdgcn_s_setprio(1);
#pragma unroll
  for (int ci = 0; ci < 2; ++ci) {
    const int ch = (2 * w + ci) * 16 + c;
    const float vb = v_bias[ch];
    f32x4 vacc[4];
#pragma unroll
    for (int mt = 0; mt < 4; ++mt) vacc[mt] = f32x4{vb, vb, vb, vb};
#pragma unroll
    for (int ks = 0; ks < 4; ++ks) {
      bf16x8 bw = *reinterpret_cast<const bf16x8*>(wv + ch * 128 + ks * 32 + g * 8);
#pragma unroll
      for (int mt = 0; mt < 4; ++mt) {
        bf16x8 xf = *reinterpret_cast<const bf16x8*>(LDS + XB + sw256(mt * 16 + c, (ks * 32 + g * 8) * 2));
        vacc[mt] = MFMA(xf, bw, vacc[mt]);
      }
    }
#pragma unroll
    for (int mt = 0; mt < 4; ++mt)
      *reinterpret_cast<unsigned long long*>(LDS + VT + sw128(ch, (mt * 16 + g * 4) * 2)) =
          pack4v(vacc[mt]);
  }
  __builtin_amdgcn_s_setprio(0);

  // S + softmax, all-register: per query tile rt, S^T tile via 2-deep MFMA16
  // over head-dim subtiles; rel-pos bias as acc-init; exp2/tree-sum/rcp.
  short4v pk[4][4];
#pragma unroll
  for (int rt = 0; rt < 4; ++rt) {
    f32x4 bbr[4];
    {
      const float* bp = biasNN + ((w * 64 + rt * 16 + c) << 6);
#pragma unroll
      for (int mt = 0; mt < 4; ++mt)
        bbr[mt] = *reinterpret_cast<const f32x4*>(bp + mt * 16 + g * 4);
    }
    f32x4 s[4];
    __builtin_amdgcn_s_setprio(1);
#pragma unroll
    for (int mt = 0; mt < 4; ++mt)
      s[mt] = MFMA16(k16[1][mt], q16[1][rt], MFMA16(k16[0][mt], q16[0][rt], bbr[mt]));
    __builtin_amdgcn_s_setprio(0);
    float v[16];
#pragma unroll
    for (int mt = 0; mt < 4; ++mt) {
#pragma unroll
      for (int j = 0; j < 4; ++j) v[mt * 4 + j] = exp2f(s[mt][j]);
    }
    float p0 = (v[0] + v[1]) + (v[2] + v[3]);
    float p1 = (v[4] + v[5]) + (v[6] + v[7]);
    float p2 = (v[8] + v[9]) + (v[10] + v[11]);
    float p3 = (v[12] + v[13]) + (v[14] + v[15]);
    float sum = (p0 + p1) + (p2 + p3);
    sum += __shfl_xor(sum, 16);
    sum += __shfl_xor(sum, 32);
    const float inv = __builtin_amdgcn_rcpf(sum);
#pragma unroll
    for (int mt = 0; mt < 4; ++mt)
      pk[rt][mt] = pack4s(v[mt * 4] * inv, v[mt * 4 + 1] * inv,
                          v[mt * 4 + 2] * inv, v[mt * 4 + 3] * inv);
  }

  // PV: O^T = V^T @ P^T via 32 x MFMA16 (A = own vt rows; B = in-register P).
  f32x4 od[2][4];
  {
    short4v vfrag[2][4];
#pragma unroll
    for (int ct = 0; ct < 2; ++ct)
#pragma unroll
      for (int mt = 0; mt < 4; ++mt)
        vfrag[ct][mt] = *reinterpret_cast<const short4v*>(
            LDS + VT + sw128((2 * w + ct) * 16 + c, (mt * 16 + g * 4) * 2));
#pragma unroll
    for (int ct = 0; ct < 2; ++ct)
#pragma unroll
      for (int rt = 0; rt < 4; ++rt) od[ct][rt] = f32x4{0.f, 0.f, 0.f, 0.f};
    __builtin_amdgcn_s_setprio(1);
#pragma unroll
    for (int mt = 0; mt < 4; ++mt)
#pragma unroll
      for (int ct = 0; ct < 2; ++ct)
#pragma unroll
        for (int rt = 0; rt < 4; ++rt)
          od[ct][rt] = MFMA16(vfrag[ct][mt], pk[rt][mt], od[ct][rt]);
    __builtin_amdgcn_s_setprio(0);
  }

  // Hoist proj weights/bias before ob writes (latency drains under B4).
  bf16x8 ap[2][4];
  f32x4 pb4[2];
#pragma unroll
  for (int u = 0; u < 2; ++u) {
    const unsigned short* wrow = wp + ((2 * w + u) * 16 + c) * 128 + g * 8;
#pragma unroll
    for (int ks = 0; ks < 4; ++ks) ap[u][ks] = *reinterpret_cast<const bf16x8*>(wrow + ks * 32);
    pb4[u] = *reinterpret_cast<const f32x4*>(proj_bias + (2 * w + u) * 16 + g * 4);
  }

  // ob writes -> OB [tok][ch] (own ch cols).
#pragma unroll
  for (int ct = 0; ct < 2; ++ct)
#pragma unroll
    for (int rt = 0; rt < 4; ++rt)
      *reinterpret_cast<unsigned long long*>(
          LDS + OB + sw256(rt * 16 + c, ((2 * w + ct) * 16 + g * 4) * 2)) = pack4v(od[ct][rt]);
  __syncthreads();  // B4: ob visible (the only cross-head dependency)

  // Phase 3: out^T = Wp @ O^T; wave w: outch tiles {2w,2w+1}; proj-bias acc-init.
  __builtin_amdgcn_s_setprio(1);
#pragma unroll
  for (int u = 0; u < 2; ++u) {
    f32x4 acc[4];
#pragma unroll
    for (int nt = 0; nt < 4; ++nt) acc[nt] = pb4[u];
#pragma unroll
    for (int ks = 0; ks < 4; ++ks) {
#pragma unroll
      for (int nt = 0; nt < 4; ++nt) {
        bf16x8 bf = *reinterpret_cast<const bf16x8*>(LDS + OB + sw256(nt * 16 + c, (ks * 32 + g * 8) * 2));
        acc[nt] = MFMA(ap[u][ks], bf, acc[nt]);
      }
    }
#pragma unroll
    for (int nt = 0; nt < 4; ++nt) {
      const int tok = nt * 16 + c;
      if (tok < 49) {
        *reinterpret_cast<f32x4*>(out + ((size_t)b * 49 + tok) * 128 + (2 * w + u) * 16 + g * 4) = acc[nt];
      }
    }
  }
  __builtin_amdgcn_s_setprio(0);
}

extern "C" void kernel_launch(void* const* d_in, const int* in_sizes, int n_in,
                              void* d_out, int out_size, void* d_ws, size_t ws_size,
                              hipStream_t stream) {
  const float* x          = (const float*)d_in[0];
  const float* qk_w       = (const float*)d_in[1];
  const float* qk_b       = (const float*)d_in[2];
  const float* v_w        = (const float*)d_in[3];
  const float* v_b        = (const float*)d_in[4];
  const float* proj_w     = (const float*)d_in[5];
  const float* proj_b     = (const float*)d_in[6];
  const float* bias_table = (const float*)d_in[7];
  float* out = (float*)d_out;

  // workspace carve: wqk bf16 [256*128] | wv [128*128] | wp [128*128] | biasNN f32 [4*64*64]
  unsigned short* wqk = (unsigned short*)d_ws;
  unsigned short* wv  = wqk + 256 * 128;
  unsigned short* wp  = wv + 128 * 128;
  float* biasNN = (float*)((char*)d_ws + 131072);

  const int B = in_sizes[0] / (49 * 128);

  rsa_prep<<<dim3(128), dim3(512), 0, stream>>>(qk_w, v_w, proj_w, bias_table, wqk, wv, wp, biasNN);
  rsa_main<<<dim3(B), dim3(256), 0, stream>>>(x, qk_b, v_b, proj_b, wqk, wv, wp, biasNN, out);
}

// Round 17
// 119.049 us; speedup vs baseline: 1.0544x; 1.0270x over previous
//
#include <hip/hip_runtime.h>
#include <hip/hip_bf16.h>

typedef __attribute__((ext_vector_type(8))) __bf16 bf16x8;
typedef __attribute__((ext_vector_type(4))) short short4v;
typedef __attribute__((ext_vector_type(4))) float f32x4;

#define MFMA(a,b,c) __builtin_amdgcn_mfma_f32_16x16x32_bf16((a),(b),(c),0,0,0)
// K=16 bf16 MFMA (v_mfma_f32_16x16x16_bf16): A/B-frag = 4 bf16 (2 VGPRs):
// A[row=c][k=g*4+j], B[k=g*4+j][col=c], D[row=g*4+j][col=c].
#define MFMA16(a,b,c) __builtin_amdgcn_mfma_f32_16x16x16bf16_1k((a),(b),(c),0,0,0)

// LDS layout (64 KB total, static):
//  XB 0..16K   : x  [64][128] bf16 (swz) -> later ob [64][128] (attention out)
//  QB 16K..32K : q  [64][128] bf16 (swz)
//  KB 32K..48K : k  [64][128] bf16 (swz)
//  VT 48K..64K : v^T [128][64] bf16 (swz)  (b64 granules = PV A-frags)
#define XB 0u
#define QB 16384u
#define KB 32768u
#define VT 49152u

static __device__ __forceinline__ unsigned short f2u(float x) {
  return __builtin_bit_cast(unsigned short, static_cast<__bf16>(x));
}
// cvt_pk-friendly packs (compiler emits v_cvt_pk_bf16_f32).
static __device__ __forceinline__ unsigned long long pack4(float a, float b, float c, float d) {
  union { __bf16 h[4]; unsigned long long u; } z;
  z.h[0] = static_cast<__bf16>(a);
  z.h[1] = static_cast<__bf16>(b);
  z.h[2] = static_cast<__bf16>(c);
  z.h[3] = static_cast<__bf16>(d);
  return z.u;
}
static __device__ __forceinline__ unsigned long long pack4v(f32x4 v) {
  return pack4(v[0], v[1], v[2], v[3]);
}
static __device__ __forceinline__ short4v pack4s(float a, float b, float c, float d) {
  union { __bf16 h[4]; short4v s; } z;
  z.h[0] = static_cast<__bf16>(a);
  z.h[1] = static_cast<__bf16>(b);
  z.h[2] = static_cast<__bf16>(c);
  z.h[3] = static_cast<__bf16>(d);
  return z.s;
}
static __device__ __forceinline__ unsigned sw256(unsigned row, unsigned colb) {
  return (row << 8) + (colb ^ ((row & 7u) << 4));
}
static __device__ __forceinline__ unsigned sw128(unsigned row, unsigned colb) {
  return (row << 7) + (colb ^ ((row & 7u) << 4));
}

// ---------------- prep: weights -> bf16 (Wq pre-scaled), bias gather ----------------
__global__ void rsa_prep(const float* __restrict__ qk_w, const float* __restrict__ v_w,
                         const float* __restrict__ proj_w, const float* __restrict__ bias_table,
                         unsigned short* __restrict__ wqk, unsigned short* __restrict__ wv,
                         unsigned short* __restrict__ wp, float* __restrict__ biasNN) {
  const float SCALE = 0.17677669529663687f;  // 32^-0.5, folded into Wq
  int t = blockIdx.x * blockDim.x + threadIdx.x;
  int stride = gridDim.x * blockDim.x;
  for (int i = t; i < 256 * 128; i += stride) {
    float v = qk_w[i];
    if (i < 128 * 128) v *= SCALE;           // q-half pre-scaled
    wqk[i] = f2u(v);
  }
  for (int i = t; i < 128 * 128; i += stride) wv[i] = f2u(v_w[i]);
  for (int i = t; i < 128 * 128; i += stride) wp[i] = f2u(proj_w[i]);
  for (int i = t; i < 4 * 64 * 64; i += stride) {
    int h = i >> 12, r = (i >> 6) & 63, m = i & 63;
    float v = -1e9f;
    if (r < 49 && m < 49) {
      int ri = r / 7, rj = r - ri * 7, mi = m / 7, mj = m - mi * 7;
      int rel = (ri - mi + 6) * 13 + (rj - mj + 6);
      v = bias_table[rel * 4 + h];
    }
    biasNN[i] = v;
  }
}

// ---------------- main: one window per block, 8 waves, 3 barriers ----------------
// Session plateau note (rounds 0-15): 7 structural variants (persistent blocks,
// fused QKV, 48KB/3-blocks-CU diet, pair-local 2-barrier, wave=head 4-wave,
// all-register q/k/S/P) all land 119-125us. No counter saturates: HBM 13%,
// MfmaUtil 13.5%, VALUBusy 29%, LDS-BW cut 2.7x had no effect, occupancy
// 41%->58% had no effect. The limiter is unoverlapped composite latency of
// short serial phases (49-token windows). This version is the measured best.
__global__ __launch_bounds__(512, 4) void rsa_main(
    const float* __restrict__ x, const float* __restrict__ qk_bias,
    const float* __restrict__ v_bias, const float* __restrict__ proj_bias,
    const unsigned short* __restrict__ wqk, const unsigned short* __restrict__ wv,
    const unsigned short* __restrict__ wp, const float* __restrict__ biasNN,
    float* __restrict__ out) {
  __shared__ __align__(16) unsigned char LDS[65536];
  const int tid = threadIdx.x;
  const int w = tid >> 6;
  const int lane = tid & 63;
  const int c = lane & 15;
  const int g = lane >> 4;
  const int b = blockIdx.x;
  const float SCALE = 0.17677669529663687f;  // only for the q-bias

  // Phase 0: stage x (49x128 f32) -> bf16 LDS [64][128] swizzled, zero-pad rows 49..63
  {
    const f32x4* xp = reinterpret_cast<const f32x4*>(x + (size_t)b * 6272);
    for (int i = tid; i < 1568; i += 512) {
      f32x4 v = xp[i];
      unsigned row = (unsigned)i >> 5, c4 = (unsigned)i & 31u;
      *reinterpret_cast<unsigned long long*>(LDS + XB + sw256(row, c4 * 8)) = pack4v(v);
    }
    for (int i = tid; i < 480; i += 512) {
      unsigned row = 49 + ((unsigned)i >> 5), c4 = (unsigned)i & 31u;
      *reinterpret_cast<unsigned long long*>(LDS + XB + sw256(row, c4 * 8)) = 0ull;
    }
  }
  __syncthreads();  // B1: x visible

  // Phase 1a: [q;k]^T = Wqk @ X^T (output-transposed). Wave w: chout tiles {w, w+8}.
  __builtin_amdgcn_s_setprio(1);
#pragma unroll
  for (int mi = 0; mi < 2; ++mi) {
    const int mt = w + 8 * mi;
    bf16x8 a[4];
    const unsigned short* wrow = wqk + (mt * 16 + c) * 128 + g * 8;
#pragma unroll
    for (int ks = 0; ks < 4; ++ks) a[ks] = *reinterpret_cast<const bf16x8*>(wrow + ks * 32);
    f32x4 bias4 = *reinterpret_cast<const f32x4*>(qk_bias + mt * 16 + g * 4);
    if (mi == 0) { bias4[0] *= SCALE; bias4[1] *= SCALE; bias4[2] *= SCALE; bias4[3] *= SCALE; }
#pragma unroll
    for (int nt = 0; nt < 4; ++nt) {
      f32x4 acc = {0.f, 0.f, 0.f, 0.f};
#pragma unroll
      for (int ks = 0; ks < 4; ++ks) {
        bf16x8 bf = *reinterpret_cast<const bf16x8*>(LDS + XB + sw256(nt * 16 + c, (ks * 32 + g * 8) * 2));
        acc = MFMA(a[ks], bf, acc);
      }
      const unsigned tok = nt * 16 + c;
      const unsigned colb = ((mt & 7) * 16 + g * 4) * 2;
      const unsigned base = (mi == 0) ? QB : KB;
      *reinterpret_cast<unsigned long long*>(LDS + base + sw256(tok, colb)) =
          pack4(acc[0] + bias4[0], acc[1] + bias4[1], acc[2] + bias4[2], acc[3] + bias4[3]);
    }
  }

  // Phase 1b: V = X @ Wv^T, stored transposed vt[ch][tok] (b64-granular frag store)
  {
    const float vb = v_bias[w * 16 + c];
    bf16x8 bw[4];
    const unsigned short* wrow = wv + (w * 16 + c) * 128 + g * 8;
#pragma unroll
    for (int ks = 0; ks < 4; ++ks) bw[ks] = *reinterpret_cast<const bf16x8*>(wrow + ks * 32);
#pragma unroll
    for (int mt = 0; mt < 4; ++mt) {
      f32x4 acc = {0.f, 0.f, 0.f, 0.f};
#pragma unroll
      for (int ks = 0; ks < 4; ++ks) {
        bf16x8 af = *reinterpret_cast<const bf16x8*>(LDS + XB + sw256(mt * 16 + c, (ks * 32 + g * 8) * 2));
        acc = MFMA(af, bw[ks], acc);
      }
      const unsigned row = w * 16 + c;              // channel
      const unsigned colb = (mt * 16 + g * 4) * 2;  // token byte offset
      *reinterpret_cast<unsigned long long*>(LDS + VT + sw128(row, colb)) =
          pack4(acc[0] + vb, acc[1] + vb, acc[2] + vb, acc[3] + vb);
    }
  }
  __builtin_amdgcn_s_setprio(0);
  __syncthreads();  // B2: q,k,vt visible

  // Phase 2a: S^T = K @ Q^T per head (wave pair: h = w>>1, half owns rt {2h..}).
  const int h = w >> 1;
  const int rt0 = (w & 1) * 2;

  // Bias rows prefetched BEFORE the S-MFMAs so L2 latency hides under them.
  f32x4 bb[2][4];
#pragma unroll
  for (int r2 = 0; r2 < 2; ++r2) {
    const int r = (rt0 + r2) * 16 + c;
    const float* bp = biasNN + ((h * 64 + r) << 6);
#pragma unroll
    for (int mt = 0; mt < 4; ++mt)
      bb[r2][mt] = *reinterpret_cast<const f32x4*>(bp + mt * 16 + g * 4);
  }

  f32x4 s[2][4];
  __builtin_amdgcn_s_setprio(1);
#pragma unroll
  for (int r2 = 0; r2 < 2; ++r2) {
    const int rt = rt0 + r2;
    bf16x8 qf = *reinterpret_cast<const bf16x8*>(LDS + QB + sw256(rt * 16 + c, h * 64 + g * 16));
#pragma unroll
    for (int mt = 0; mt < 4; ++mt) {
      bf16x8 kf = *reinterpret_cast<const bf16x8*>(LDS + KB + sw256(mt * 16 + c, h * 64 + g * 16));
      f32x4 z = {0.f, 0.f, 0.f, 0.f};
      s[r2][mt] = MFMA(kf, qf, z);
    }
  }
  __builtin_amdgcn_s_setprio(0);
  // NO barrier: P stays in registers; q/k are never overwritten.

  // Phase 2b: softmax -> P kept in-register as 16x16x16 B-frags pk[r2][mt]
  // (lane (c,g) holds P[r][mt*16+g*4+j], j=0..3 — exactly the K=16 B-fragment).
  short4v pk[2][4];
#pragma unroll
  for (int r2 = 0; r2 < 2; ++r2) {
    float v[16];
    float sum = 0.f;
#pragma unroll
    for (int mt = 0; mt < 4; ++mt) {
#pragma unroll
      for (int j = 0; j < 4; ++j) {
        v[mt * 4 + j] = __expf(s[r2][mt][j] + bb[r2][mt][j]);
        sum += v[mt * 4 + j];
      }
    }
    sum += __shfl_xor(sum, 16);
    sum += __shfl_xor(sum, 32);
    const float inv = (sum > 0.f) ? 1.0f / sum : 0.f;
#pragma unroll
    for (int mt = 0; mt < 4; ++mt)
      pk[r2][mt] = pack4s(v[mt * 4] * inv, v[mt * 4 + 1] * inv,
                          v[mt * 4 + 2] * inv, v[mt * 4 + 3] * inv);
  }

  // Phase 2c: O^T = V^T @ P^T via 16 x mfma16. A-frags are b64 reads from vt
  // (4 consecutive tokens at one channel row — same swizzled layout as stored).
  f32x4 od[2][2];
  {
    short4v vfrag[2][4];
#pragma unroll
    for (int ct2 = 0; ct2 < 2; ++ct2)
#pragma unroll
      for (int ks = 0; ks < 4; ++ks)
        vfrag[ct2][ks] = *reinterpret_cast<const short4v*>(
            LDS + VT + sw128((h * 2 + ct2) * 16 + c, (ks * 16 + g * 4) * 2));
    __builtin_amdgcn_s_setprio(1);
#pragma unroll
    for (int ct2 = 0; ct2 < 2; ++ct2)
#pragma unroll
      for (int r2 = 0; r2 < 2; ++r2) {
        f32x4 acc = {0.f, 0.f, 0.f, 0.f};
#pragma unroll
        for (int ks = 0; ks < 4; ++ks) acc = MFMA16(vfrag[ct2][ks], pk[r2][ks], acc);
        od[ct2][r2] = acc;
      }
    __builtin_amdgcn_s_setprio(0);
  }

  // Hoist phase-3 weight/bias loads: their L2 latency drains under the
  // ob writes + B4 barrier wait.
  bf16x8 ap[4];
  {
    const unsigned short* wrow = wp + (w * 16 + c) * 128 + g * 8;
#pragma unroll
    for (int ks = 0; ks < 4; ++ks) ap[ks] = *reinterpret_cast<const bf16x8*>(wrow + ks * 32);
  }
  f32x4 pb4 = *reinterpret_cast<const f32x4*>(proj_bias + w * 16 + g * 4);

  // ob writes (aliases XB; x dead since B2): ob[tok][ch], b64 per (ct,rt) tile.
#pragma unroll
  for (int ct2 = 0; ct2 < 2; ++ct2)
#pragma unroll
    for (int r2 = 0; r2 < 2; ++r2) {
      const int r = (rt0 + r2) * 16 + c;
      *reinterpret_cast<unsigned long long*>(
          LDS + XB + sw256(r, ((h * 2 + ct2) * 16 + g * 4) * 2)) = pack4v(od[ct2][r2]);
    }
  __syncthreads();  // B4: ob visible

  // Phase 3: out^T = Wp @ O^T; f32x4 stores to global
  {
    __builtin_amdgcn_s_setprio(1);
#pragma unroll
    for (int nt = 0; nt < 4; ++nt) {
      f32x4 acc = {0.f, 0.f, 0.f, 0.f};
#pragma unroll
      for (int ks = 0; ks < 4; ++ks) {
        bf16x8 bf = *reinterpret_cast<const bf16x8*>(LDS + XB + sw256(nt * 16 + c, (ks * 32 + g * 8) * 2));
        acc = MFMA(ap[ks], bf, acc);
      }
      const int tok = nt * 16 + c;
      if (tok < 49) {
        f32x4 o = {acc[0] + pb4[0], acc[1] + pb4[1], acc[2] + pb4[2], acc[3] + pb4[3]};
        *reinterpret_cast<f32x4*>(out + ((size_t)b * 49 + tok) * 128 + w * 16 + g * 4) = o;
      }
    }
    __builtin_amdgcn_s_setprio(0);
  }
}

extern "C" void kernel_launch(void* const* d_in, const int* in_sizes, int n_in,
                              void* d_out, int out_size, void* d_ws, size_t ws_size,
                              hipStream_t stream) {
  const float* x          = (const float*)d_in[0];
  const float* qk_w       = (const float*)d_in[1];
  const float* qk_b       = (const float*)d_in[2];
  const float* v_w        = (const float*)d_in[3];
  const float* v_b        = (const float*)d_in[4];
  const float* proj_w     = (const float*)d_in[5];
  const float* proj_b     = (const float*)d_in[6];
  const float* bias_table = (const float*)d_in[7];
  float* out = (float*)d_out;

  // workspace carve: wqk bf16 [256*128] | wv [128*128] | wp [128*128] | biasNN f32 [4*64*64]
  unsigned short* wqk = (unsigned short*)d_ws;
  unsigned short* wv  = wqk + 256 * 128;
  unsigned short* wp  = wv + 128 * 128;
  float* biasNN = (float*)((char*)d_ws + 131072);

  const int B = in_sizes[0] / (49 * 128);

  rsa_prep<<<dim3(256), dim3(512), 0, stream>>>(qk_w, v_w, proj_w, bias_table, wqk, wv, wp, biasNN);
  rsa_main<<<dim3(B), dim3(512), 0, stream>>>(x, qk_b, v_b, proj_b, wqk, wv, wp, biasNN, out);
}